// Round 4
// baseline (119.988 us; speedup 1.0000x reference)
//
#include <hip/hip_runtime.h>
#include <hip/hip_cooperative_groups.h>

namespace cg = cooperative_groups;

// Single cooperative kernel, one graph node. No global atomics, no ws
// zero-init (every ws slot is written before read; grid.sync() orders
// producer writes before consumer reads across XCDs).
//
// Math: a_i = 1 - p_i (positives), n_j = p_j (negatives):
//   loss = [ Nn*Sum(a^2) + 2*Sum(a)*Sum(n) + P*Sum(n^2)
//            + margin * Sum_{i,j} relu(a_i + n_j) ] / (P*Nn)
//
// ws layout:
//   [0     .. 8192)   double momPart[256][4]
//   [8192  .. 9216)   int    cnt[256]        (positives per 64-elem segment)
//   [9216  .. 11264)  double reluPart[256]
//   [11264 .. 76800)  float  posSeg[256*64]  (per-segment compacted a_i)

#define NBLK 256
#define SEG  64          // elements per segment == one wave's ballot width
#define MAXS 4096        // max positives per quarter-slice (N/4); 16 KB LDS

__device__ __forceinline__ double wave_reduce_f64(double v) {
    #pragma unroll
    for (int off = 32; off > 0; off >>= 1) v += __shfl_xor(v, off, 64);
    return v;
}

__device__ __forceinline__ float wave_reduce_f32(float v) {
    #pragma unroll
    for (int off = 32; off > 0; off >>= 1) v += __shfl_xor(v, off, 64);
    return v;
}

__global__ __launch_bounds__(256)
void aucm_coop(const float* __restrict__ preds,
               const int* __restrict__ tgt,
               int n,
               double* __restrict__ momPart,   // [NBLK][4]
               int* __restrict__ cnt,          // [NBLK]
               double* __restrict__ reluPart,  // [NBLK]
               float* __restrict__ posSeg,     // [NBLK*SEG]
               float* __restrict__ out,
               float margin) {
    cg::grid_group grid = cg::this_grid();

    __shared__ float sList[MAXS];
    __shared__ int   sWaveSum[4];
    __shared__ double sRed[4][6];

    const int tid  = threadIdx.x;
    const int lane = tid & 63;
    const int wave = tid >> 6;
    const int b    = blockIdx.x;

    // ---- Phase 1: wave 0 compacts segment [b*SEG, b*SEG+SEG) via ballot ----
    if (wave == 0) {
        const int i = b * SEG + lane;
        float p = 0.f; int t = 0;
        if (i < n) { p = preds[i]; t = tgt[i]; }
        const bool isPos = (i < n) && (t == 1);
        const float av = 1.0f - p;
        const unsigned long long mask = __ballot(isPos);
        const int pfx = __popcll(mask & ((1ull << lane) - 1ull));
        if (isPos) posSeg[b * SEG + pfx] = av;

        float a  = isPos ? av : 0.f;
        float a2 = isPos ? av * av : 0.f;
        float nv = (!isPos && i < n) ? p : 0.f;
        float n2 = (!isPos && i < n) ? p * p : 0.f;
        const float rA  = wave_reduce_f32(a);
        const float rA2 = wave_reduce_f32(a2);
        const float rN  = wave_reduce_f32(nv);
        const float rN2 = wave_reduce_f32(n2);
        if (lane == 0) {
            momPart[b * 4 + 0] = (double)rA;
            momPart[b * 4 + 1] = (double)rA2;
            momPart[b * 4 + 2] = (double)rN;
            momPart[b * 4 + 3] = (double)rN2;
            cnt[b] = __popcll(mask);
        }
    }
    grid.sync();

    // ---- Phase 2: block-wide scan of all 256 counts (redundant per block) --
    const int c = cnt[tid];                 // one segment count per thread
    int v = c;
    #pragma unroll
    for (int off = 1; off < 64; off <<= 1) {
        const int u = __shfl_up(v, off, 64);
        if (lane >= off) v += u;
    }
    if (lane == 63) sWaveSum[wave] = v;
    __syncthreads();
    int waveBase = 0;
    #pragma unroll
    for (int w = 0; w < 4; ++w) if (w < wave) waveBase += sWaveSum[w];
    const int excl  = waveBase + v - c;     // exclusive offset of segment tid
    const int total = sWaveSum[0] + sWaveSum[1] + sWaveSum[2] + sWaveSum[3];

    // Gather this block's quarter-slice [lo, hi) of the positive list.
    const int slice = b >> 6;               // 0..3
    const int per   = (total + 3) >> 2;
    const int lo    = slice * per;
    const int hi    = min(total, lo + per);
    const int cntS  = max(0, hi - lo);      // <= MAXS always
    for (int k = 0; k < c; ++k) {
        const int g = excl + k;
        if (g >= lo && g < hi) sList[g - lo] = posSeg[tid * SEG + k];
    }
    __syncthreads();

    // ---- relu pair-sum: this thread's own j over the LDS slice ----
    const int j = (b & 63) * 256 + tid;
    float acc = 0.f;
    if (j < n && tgt[j] == 0) {
        const float pj = preds[j];
        int k = 0;
        for (; k + 8 <= cntS; k += 8) {
            #pragma unroll
            for (int u = 0; u < 8; ++u)
                acc += fmaxf(sList[k + u] + pj, 0.f);
        }
        for (; k < cntS; ++k) acc += fmaxf(sList[k] + pj, 0.f);
    }
    double r = wave_reduce_f64((double)acc);
    if (lane == 0) sRed[wave][0] = r;
    __syncthreads();
    if (tid == 0)
        reluPart[b] = sRed[0][0] + sRed[1][0] + sRed[2][0] + sRed[3][0];
    grid.sync();

    // ---- Phase 3: block 0 reduces everything and stores ----
    if (b == 0) {
        double mA = 0, mA2 = 0, mN = 0, mN2 = 0, rr = 0, pc = 0;
        // 256 entries, 256 threads: one each.
        mA  = momPart[tid * 4 + 0];
        mA2 = momPart[tid * 4 + 1];
        mN  = momPart[tid * 4 + 2];
        mN2 = momPart[tid * 4 + 3];
        rr  = reluPart[tid];
        pc  = (double)cnt[tid];
        mA = wave_reduce_f64(mA);  mA2 = wave_reduce_f64(mA2);
        mN = wave_reduce_f64(mN);  mN2 = wave_reduce_f64(mN2);
        rr = wave_reduce_f64(rr);  pc  = wave_reduce_f64(pc);
        if (lane == 0) {
            sRed[wave][0] = mA; sRed[wave][1] = mA2; sRed[wave][2] = mN;
            sRed[wave][3] = mN2; sRed[wave][4] = rr; sRed[wave][5] = pc;
        }
        __syncthreads();
        if (tid == 0) {
            double tA = 0, tA2 = 0, tN = 0, tN2 = 0, tR = 0, tP = 0;
            #pragma unroll
            for (int w = 0; w < 4; ++w) {
                tA += sRed[w][0]; tA2 += sRed[w][1]; tN += sRed[w][2];
                tN2 += sRed[w][3]; tR += sRed[w][4]; tP += sRed[w][5];
            }
            const double P  = tP;
            const double Nn = (double)n - tP;
            const double sq = Nn * tA2 + 2.0 * tA * tN + P * tN2;
            out[0] = (float)((sq + (double)margin * tR) / (P * Nn));
        }
    }
}

extern "C" void kernel_launch(void* const* d_in, const int* in_sizes, int n_in,
                              void* d_out, int out_size, void* d_ws, size_t ws_size,
                              hipStream_t stream) {
    const float* preds = (const float*)d_in[0];
    const int*   tgt   = (const int*)d_in[1];
    float* out = (float*)d_out;
    int n = in_sizes[0];   // 16384 == NBLK * SEG

    char* ws = (char*)d_ws;
    double* momPart  = (double*)(ws + 0);
    int*    cnt      = (int*)(ws + 8192);
    double* reluPart = (double*)(ws + 9216);
    float*  posSeg   = (float*)(ws + 11264);
    float margin = 1.0f;

    void* args[] = { (void*)&preds, (void*)&tgt, (void*)&n,
                     (void*)&momPart, (void*)&cnt, (void*)&reluPart,
                     (void*)&posSeg, (void*)&out, (void*)&margin };
    hipLaunchCooperativeKernel((void*)aucm_coop, dim3(NBLK), dim3(256),
                               args, 0, stream);
}

// Round 5
// 70.608 us; speedup vs baseline: 1.6993x; 1.6993x over previous
//
#include <hip/hip_runtime.h>

// Two kernels, two graph nodes:
//  1) aucm_scan: 64 blocks, 1 elem/thread — ballot-free LDS compaction of
//     positives into per-segment global lists + moment partials + zeroes the
//     completion counter for kernel 2.
//  2) aucm_relu_fin: 256 blocks (64 j-blocks x 4 i-slices) — relu pair-sum
//     per j over an LDS-staged positive slice; last block (device-scope
//     completion counter + threadfence release/acquire) reduces everything
//     and writes the loss. No grid.sync (measured 2x grid.sync ~= 40us on
//     this chip — kernel boundaries are cheaper), no ws zero-init reliance.
//
// Math: a_i = 1 - p_i (positives), n_j = p_j (negatives):
//   loss = [ Nn*Sum(a^2) + 2*Sum(a)*Sum(n) + P*Sum(n^2)
//            + margin * Sum_{i,j} relu(a_i + n_j) ] / (P*Nn)
//
// ws layout (every slot written before read):
//   [0    .. 2048)  double momPart[64][4]
//   [2048 .. 2304)  int    cnt[64]
//   [2304 .. 4352)  double reluPart[256]
//   [4352 .. 4356)  int    done          (zeroed by aucm_scan)
//   [4608 .. 70144) float  posSeg[64][256]

#define NSEG  64
#define MAXP  4096   // max positives per quarter-slice (N/4); 16 KB LDS

__device__ __forceinline__ double wave_reduce_f64(double v) {
    #pragma unroll
    for (int off = 32; off > 0; off >>= 1) v += __shfl_xor(v, off, 64);
    return v;
}

__device__ __forceinline__ float wave_reduce_f32(float v) {
    #pragma unroll
    for (int off = 32; off > 0; off >>= 1) v += __shfl_xor(v, off, 64);
    return v;
}

// ---------------------------------------------------------------------------
// Kernel 1: 64 blocks x 256 threads, exactly one element per thread.
__global__ __launch_bounds__(256)
void aucm_scan(const float* __restrict__ preds,
               const int* __restrict__ tgt,
               int n,
               double* __restrict__ momPart,  // [NSEG][4]
               int* __restrict__ cnt,         // [NSEG]
               float* __restrict__ posSeg,    // [NSEG][256]
               int* __restrict__ done) {
    __shared__ float sPos[256];
    __shared__ int sCnt;
    __shared__ double sRed[4][4];

    const int tid  = threadIdx.x;
    const int b    = blockIdx.x;
    const int wave = tid >> 6;
    if (tid == 0) sCnt = 0;
    __syncthreads();

    const int i = b * 256 + tid;
    float a = 0.f, a2 = 0.f, nv = 0.f, n2 = 0.f;
    if (i < n) {
        const float p = preds[i];
        if (tgt[i] == 1) {
            const float av = 1.0f - p;
            a = av; a2 = av * av;
            const int idx = atomicAdd(&sCnt, 1);   // LDS-scope ticket
            sPos[idx] = av;
        } else {
            nv = p; n2 = p * p;
        }
    }
    __syncthreads();
    const int c = sCnt;
    if (tid < c) posSeg[b * 256 + tid] = sPos[tid];

    const float rA  = wave_reduce_f32(a);
    const float rA2 = wave_reduce_f32(a2);
    const float rN  = wave_reduce_f32(nv);
    const float rN2 = wave_reduce_f32(n2);
    if ((tid & 63) == 0) {
        sRed[wave][0] = (double)rA;  sRed[wave][1] = (double)rA2;
        sRed[wave][2] = (double)rN;  sRed[wave][3] = (double)rN2;
    }
    __syncthreads();
    if (tid == 0) {
        double t0 = 0, t1 = 0, t2 = 0, t3 = 0;
        #pragma unroll
        for (int w = 0; w < 4; ++w) {
            t0 += sRed[w][0]; t1 += sRed[w][1];
            t2 += sRed[w][2]; t3 += sRed[w][3];
        }
        momPart[b * 4 + 0] = t0; momPart[b * 4 + 1] = t1;
        momPart[b * 4 + 2] = t2; momPart[b * 4 + 3] = t3;
        cnt[b] = c;
        if (b == 0) *done = 0;   // visible to kernel 2 via kernel boundary
    }
}

// ---------------------------------------------------------------------------
// Kernel 2: 256 blocks = 64 j-blocks x 4 i-slices, 256 threads.
// relu pair-sum + last-block finalize.
__global__ __launch_bounds__(256)
void aucm_relu_fin(const float* __restrict__ preds,
                   const int* __restrict__ tgt,
                   int n,
                   const int* __restrict__ cnt,
                   const float* __restrict__ posSeg,
                   const double* __restrict__ momPart,
                   double* __restrict__ reluPart,
                   int* __restrict__ done,
                   float* __restrict__ out, float margin) {
    __shared__ int pref[NSEG + 1];
    __shared__ float sA[MAXP];
    __shared__ double sRed[4];
    __shared__ double sFin[4][6];
    __shared__ int sIsLast;

    const int tid   = threadIdx.x;
    const int wave  = tid >> 6;
    const int jb    = blockIdx.x & 63;   // j-block (0..63)
    const int slice = blockIdx.x >> 6;   // i-slice (0..3)

    if (tid == 0) {
        int run = 0;
        for (int s = 0; s < NSEG; ++s) { pref[s] = run; run += cnt[s]; }
        pref[NSEG] = run;
    }
    __syncthreads();

    const int total = pref[NSEG];
    const int per   = (total + 3) >> 2;
    const int lo    = slice * per;
    const int hi    = min(total, lo + per);
    const int cntS  = max(0, hi - lo);

    // Gather slice [lo, hi) into LDS via binary search over the prefix.
    for (int s = tid; s < cntS; s += 256) {
        const int g = lo + s;
        int l = 0, h = NSEG;
        while (h - l > 1) { const int m = (l + h) >> 1; if (pref[m] <= g) l = m; else h = m; }
        sA[s] = posSeg[l * 256 + (g - pref[l])];
    }
    __syncthreads();

    const int j = jb * 256 + tid;
    float acc = 0.f;
    if (j < n && tgt[j] == 0) {
        const float pj = preds[j];
        int k = 0;
        for (; k + 8 <= cntS; k += 8) {
            #pragma unroll
            for (int u = 0; u < 8; ++u)
                acc += fmaxf(sA[k + u] + pj, 0.f);
        }
        for (; k < cntS; ++k) acc += fmaxf(sA[k] + pj, 0.f);
    }

    double r = wave_reduce_f64((double)acc);
    if ((tid & 63) == 0) sRed[wave] = r;
    __syncthreads();
    if (tid == 0) {
        reluPart[blockIdx.x] = sRed[0] + sRed[1] + sRed[2] + sRed[3];
        __threadfence();                       // release reluPart[b]
        const int t = atomicAdd(done, 1);      // device-scope
        sIsLast = (t == (int)gridDim.x - 1);
    }
    __syncthreads();
    if (!sIsLast) return;

    // ---- Last block: reduce moments + counts + relu partials, store. ----
    __threadfence();                           // acquire others' writes
    double mA = 0, mA2 = 0, mN = 0, mN2 = 0, pc = 0;
    if (tid < NSEG) {
        mA  = momPart[tid * 4 + 0]; mA2 = momPart[tid * 4 + 1];
        mN  = momPart[tid * 4 + 2]; mN2 = momPart[tid * 4 + 3];
        pc  = (double)cnt[tid];
    }
    double rr = reluPart[tid];                 // 256 partials, one per thread
    mA = wave_reduce_f64(mA);  mA2 = wave_reduce_f64(mA2);
    mN = wave_reduce_f64(mN);  mN2 = wave_reduce_f64(mN2);
    rr = wave_reduce_f64(rr);  pc  = wave_reduce_f64(pc);
    if ((tid & 63) == 0) {
        sFin[wave][0] = mA; sFin[wave][1] = mA2; sFin[wave][2] = mN;
        sFin[wave][3] = mN2; sFin[wave][4] = rr; sFin[wave][5] = pc;
    }
    __syncthreads();
    if (tid == 0) {
        double tA = 0, tA2 = 0, tN = 0, tN2 = 0, tR = 0, tP = 0;
        #pragma unroll
        for (int w = 0; w < 4; ++w) {
            tA += sFin[w][0]; tA2 += sFin[w][1]; tN += sFin[w][2];
            tN2 += sFin[w][3]; tR += sFin[w][4]; tP += sFin[w][5];
        }
        const double P  = tP;
        const double Nn = (double)n - tP;
        const double sq = Nn * tA2 + 2.0 * tA * tN + P * tN2;
        out[0] = (float)((sq + (double)margin * tR) / (P * Nn));
    }
}

// ---------------------------------------------------------------------------
extern "C" void kernel_launch(void* const* d_in, const int* in_sizes, int n_in,
                              void* d_out, int out_size, void* d_ws, size_t ws_size,
                              hipStream_t stream) {
    const float* preds = (const float*)d_in[0];
    const int*   tgt   = (const int*)d_in[1];
    float* out = (float*)d_out;
    const int n = in_sizes[0];   // 16384 == NSEG*256

    char* ws = (char*)d_ws;
    double* momPart  = (double*)(ws + 0);
    int*    cnt      = (int*)(ws + 2048);
    double* reluPart = (double*)(ws + 2304);
    int*    done     = (int*)(ws + 4352);
    float*  posSeg   = (float*)(ws + 4608);

    aucm_scan<<<NSEG, 256, 0, stream>>>(preds, tgt, n, momPart, cnt, posSeg, done);
    aucm_relu_fin<<<NSEG * 4, 256, 0, stream>>>(preds, tgt, n, cnt, posSeg,
                                                momPart, reluPart, done, out,
                                                1.0f /*MARGIN*/);
}

// Round 6
// 67.775 us; speedup vs baseline: 1.7704x; 1.0418x over previous
//
#include <hip/hip_runtime.h>

// Round-3 champion structure (3 small graph nodes — measured cheaper than
// grid.sync (R4: +50us) and cheaper than last-block atomic fusion (R5: +3.5us))
// plus negative-compaction so the hot relu kernel never touches tgt[].
//
// Math: a_i = 1 - p_i (positives), n_j = p_j (negatives):
//   loss = [ Nn*Sum(a^2) + 2*Sum(a)*Sum(n) + P*Sum(n^2)     (O(N) closed form)
//            + margin * Sum_{i,j} relu(a_i + n_j) ] / (P*Nn) (pairwise, P~1199)
//
// ws layout (every slot written before read — safe under 0xAA poison):
//   [0    .. 2048)   double momPart[64][4]
//   [2048 .. 2304)   int    cntPos[64]
//   [2304 .. 2560)   int    cntNeg[64]
//   [2560 .. 4608)   double reluPart[256]
//   [4608 .. 70144)  float  posSeg[64][256]
//   [70144.. 135680) float  negSeg[64][256]

#define NSEG  64
#define MAXP  4096   // max positives per quarter-slice (N/4 worst case); 16 KB

__device__ __forceinline__ double wave_reduce_f64(double v) {
    #pragma unroll
    for (int off = 32; off > 0; off >>= 1) v += __shfl_xor(v, off, 64);
    return v;
}

__device__ __forceinline__ float wave_reduce_f32(float v) {
    #pragma unroll
    for (int off = 32; off > 0; off >>= 1) v += __shfl_xor(v, off, 64);
    return v;
}

// ---------------------------------------------------------------------------
// Kernel 1: 64 blocks x 256 threads, one element per thread.
// Compacts positives AND negatives per segment; moment partials.
__global__ __launch_bounds__(256)
void aucm_scan(const float* __restrict__ preds,
               const int* __restrict__ tgt,
               int n,
               double* __restrict__ momPart,  // [NSEG][4]
               int* __restrict__ cntPos,      // [NSEG]
               int* __restrict__ cntNeg,      // [NSEG]
               float* __restrict__ posSeg,    // [NSEG][256]
               float* __restrict__ negSeg) {  // [NSEG][256]
    __shared__ float sPos[256];
    __shared__ float sNeg[256];
    __shared__ int sCp, sCn;
    __shared__ double sRed[4][4];

    const int tid  = threadIdx.x;
    const int b    = blockIdx.x;
    const int wave = tid >> 6;
    if (tid == 0) { sCp = 0; sCn = 0; }
    __syncthreads();

    const int i = b * 256 + tid;
    float a = 0.f, a2 = 0.f, nv = 0.f, n2 = 0.f;
    if (i < n) {
        const float p = preds[i];
        if (tgt[i] == 1) {
            const float av = 1.0f - p;
            a = av; a2 = av * av;
            sPos[atomicAdd(&sCp, 1)] = av;     // LDS-scope ticket
        } else {
            nv = p; n2 = p * p;
            sNeg[atomicAdd(&sCn, 1)] = p;
        }
    }
    __syncthreads();
    const int cp = sCp, cn = sCn;
    if (tid < cp) posSeg[b * 256 + tid] = sPos[tid];
    if (tid < cn) negSeg[b * 256 + tid] = sNeg[tid];

    const float rA  = wave_reduce_f32(a);
    const float rA2 = wave_reduce_f32(a2);
    const float rN  = wave_reduce_f32(nv);
    const float rN2 = wave_reduce_f32(n2);
    if ((tid & 63) == 0) {
        sRed[wave][0] = (double)rA;  sRed[wave][1] = (double)rA2;
        sRed[wave][2] = (double)rN;  sRed[wave][3] = (double)rN2;
    }
    __syncthreads();
    if (tid == 0) {
        double t0 = 0, t1 = 0, t2 = 0, t3 = 0;
        #pragma unroll
        for (int w = 0; w < 4; ++w) {
            t0 += sRed[w][0]; t1 += sRed[w][1];
            t2 += sRed[w][2]; t3 += sRed[w][3];
        }
        momPart[b * 4 + 0] = t0; momPart[b * 4 + 1] = t1;
        momPart[b * 4 + 2] = t2; momPart[b * 4 + 3] = t3;
        cntPos[b] = cp; cntNeg[b] = cn;
    }
}

// ---------------------------------------------------------------------------
// Kernel 2: 256 blocks = 64 j-blocks x 4 i-slices, 256 threads.
// Each thread owns one compacted negative; loops the LDS positive slice.
// LDS reads are wave-uniform -> bank broadcast, conflict-free.
__global__ __launch_bounds__(256)
void aucm_relu(const int* __restrict__ cntPos,
               const int* __restrict__ cntNeg,
               const float* __restrict__ posSeg,
               const float* __restrict__ negSeg,
               double* __restrict__ reluPart) {
    __shared__ int pref[NSEG + 1];
    __shared__ float sA[MAXP];
    __shared__ double sRed[4];

    const int tid   = threadIdx.x;
    const int jb    = blockIdx.x & 63;   // j-block (0..63)
    const int slice = blockIdx.x >> 6;   // i-slice (0..3)

    if (tid == 0) {
        int run = 0;
        for (int s = 0; s < NSEG; ++s) { pref[s] = run; run += cntPos[s]; }
        pref[NSEG] = run;
    }
    __syncthreads();

    const int total = pref[NSEG];
    const int per   = (total + 3) >> 2;
    const int lo    = slice * per;
    const int hi    = min(total, lo + per);
    const int cntS  = max(0, hi - lo);   // <= MAXP

    // Gather slice [lo, hi) into LDS via binary search over the prefix.
    for (int s = tid; s < cntS; s += 256) {
        const int g = lo + s;
        int l = 0, h = NSEG;
        while (h - l > 1) { const int m = (l + h) >> 1; if (pref[m] <= g) l = m; else h = m; }
        sA[s] = posSeg[l * 256 + (g - pref[l])];
    }
    __syncthreads();

    float acc = 0.f;
    if (tid < cntNeg[jb]) {
        const float pj = negSeg[jb * 256 + tid];
        int k = 0;
        for (; k + 8 <= cntS; k += 8) {
            #pragma unroll
            for (int u = 0; u < 8; ++u)
                acc += fmaxf(sA[k + u] + pj, 0.f);
        }
        for (; k < cntS; ++k) acc += fmaxf(sA[k] + pj, 0.f);
    }

    double r = wave_reduce_f64((double)acc);
    if ((tid & 63) == 0) sRed[tid >> 6] = r;
    __syncthreads();
    if (tid == 0)
        reluPart[blockIdx.x] = sRed[0] + sRed[1] + sRed[2] + sRed[3];
}

// ---------------------------------------------------------------------------
// Kernel 3: finalize. 1 block x 256 threads.
__global__ __launch_bounds__(256)
void aucm_fin(const double* __restrict__ momPart,
              const int* __restrict__ cntPos,
              const double* __restrict__ reluPart,
              int nRelu, int n,
              float* __restrict__ out, float margin) {
    __shared__ double sRed[4][6];
    const int tid = threadIdx.x;
    const int wave = tid >> 6;

    double mA = 0, mA2 = 0, mN = 0, mN2 = 0, r = 0, pc = 0;
    if (tid < NSEG) {
        mA  = momPart[tid * 4 + 0]; mA2 = momPart[tid * 4 + 1];
        mN  = momPart[tid * 4 + 2]; mN2 = momPart[tid * 4 + 3];
        pc  = (double)cntPos[tid];
    }
    for (int i = tid; i < nRelu; i += 256) r += reluPart[i];

    mA = wave_reduce_f64(mA);  mA2 = wave_reduce_f64(mA2);
    mN = wave_reduce_f64(mN);  mN2 = wave_reduce_f64(mN2);
    r  = wave_reduce_f64(r);   pc  = wave_reduce_f64(pc);
    if ((tid & 63) == 0) {
        sRed[wave][0] = mA; sRed[wave][1] = mA2; sRed[wave][2] = mN;
        sRed[wave][3] = mN2; sRed[wave][4] = r;  sRed[wave][5] = pc;
    }
    __syncthreads();
    if (tid == 0) {
        double tA = 0, tA2 = 0, tN = 0, tN2 = 0, tR = 0, tP = 0;
        #pragma unroll
        for (int w = 0; w < 4; ++w) {
            tA += sRed[w][0]; tA2 += sRed[w][1]; tN += sRed[w][2];
            tN2 += sRed[w][3]; tR += sRed[w][4]; tP += sRed[w][5];
        }
        const double P  = tP;
        const double Nn = (double)n - tP;
        const double sq = Nn * tA2 + 2.0 * tA * tN + P * tN2;
        out[0] = (float)((sq + (double)margin * tR) / (P * Nn));
    }
}

// ---------------------------------------------------------------------------
extern "C" void kernel_launch(void* const* d_in, const int* in_sizes, int n_in,
                              void* d_out, int out_size, void* d_ws, size_t ws_size,
                              hipStream_t stream) {
    const float* preds = (const float*)d_in[0];
    const int*   tgt   = (const int*)d_in[1];
    float* out = (float*)d_out;
    const int n = in_sizes[0];   // 16384 == NSEG*256

    char* ws = (char*)d_ws;
    double* momPart  = (double*)(ws + 0);
    int*    cntPos   = (int*)(ws + 2048);
    int*    cntNeg   = (int*)(ws + 2304);
    double* reluPart = (double*)(ws + 2560);
    float*  posSeg   = (float*)(ws + 4608);
    float*  negSeg   = (float*)(ws + 70144);

    aucm_scan<<<NSEG, 256, 0, stream>>>(preds, tgt, n, momPart, cntPos, cntNeg,
                                        posSeg, negSeg);
    aucm_relu<<<NSEG * 4, 256, 0, stream>>>(cntPos, cntNeg, posSeg, negSeg,
                                            reluPart);
    aucm_fin<<<1, 256, 0, stream>>>(momPart, cntPos, reluPart, NSEG * 4, n, out,
                                    1.0f /*MARGIN*/);
}